// Round 1
// baseline (763.586 us; speedup 1.0000x reference)
//
#include <hip/hip_runtime.h>
#include <hip/hip_bf16.h>

#define HIDDEN 128
#define NB 64
#define TG 8192             // table cells
#define TPTS (TG + 1)       // table points
#define TMAX 32.0f
#define TINV ((float)TG / TMAX)   // = 256 cells per unit of squared distance

// ---------------------------------------------------------------------------
// Kernel 1: tabulate the filter network M(d2) = relu(relu(rbf(d2)@W1)@W2)
// on a uniform grid over [0, TMAX]. One block per grid point, 128 threads.
// ---------------------------------------------------------------------------
__global__ void build_table(const float* __restrict__ W1,
                            const float* __restrict__ W2,
                            float* __restrict__ T) {
    __shared__ float rbf[NB];
    __shared__ float m1[HIDDEN];
    const int g = blockIdx.x;       // 0 .. TPTS-1
    const int c = threadIdx.x;      // 0 .. 127
    const float d = (float)g * (TMAX / (float)TG);
    if (c < NB) {
        const float center = 25.0f * (float)c / 63.0f;
        const float w = 25.0f / 63.0f;
        const float z = d - center;
        rbf[c] = expf(-(z * z) / (2.0f * w * w));
    }
    __syncthreads();
    float acc = 0.0f;
#pragma unroll
    for (int b = 0; b < NB; ++b) acc = fmaf(rbf[b], W1[b * HIDDEN + c], acc);
    m1[c] = fmaxf(acc, 0.0f);
    __syncthreads();
    float acc2 = 0.0f;
#pragma unroll 8
    for (int k = 0; k < HIDDEN; ++k) acc2 = fmaf(m1[k], W2[k * HIDDEN + c], acc2);
    T[(size_t)g * HIDDEN + c] = fmaxf(acc2, 0.0f);
}

// ---------------------------------------------------------------------------
// Kernel 2: per-edge continuous-filter conv + scatter.
// One wave (64 lanes) per edge; each lane owns 2 channels (float2).
// H[dest] += X[src] * lerp(T[g], T[g+1], t)
// ---------------------------------------------------------------------------
__global__ __launch_bounds__(256) void edge_scatter(
    const float* __restrict__ R, const int* __restrict__ src,
    const int* __restrict__ dest, const float* __restrict__ X,
    const float* __restrict__ T, float* __restrict__ H, int E) {
    const int gid = blockIdx.x * blockDim.x + threadIdx.x;
    const int e = gid >> 6;
    const int lane = threadIdx.x & 63;
    if (e >= E) return;
    const int s = src[e];
    const int d = dest[e];
    // all lanes load the same 6 floats -> wave-broadcast from L1
    const float dx = R[3 * s + 0] - R[3 * d + 0];
    const float dy = R[3 * s + 1] - R[3 * d + 1];
    const float dz = R[3 * s + 2] - R[3 * d + 2];
    const float D2 = fmaf(dx, dx, fmaf(dy, dy, dz * dz));
    float u = D2 * TINV;
    int g;
    float t;
    if (u >= (float)TG) {            // beyond table: filter is exactly 0 there
        g = TG - 1;
        t = 1.0f;
    } else {
        g = (int)u;
        t = u - (float)g;
    }
    const float2* t0 = (const float2*)(T + (size_t)g * HIDDEN);
    const float2 a = t0[lane];
    const float2 b = t0[lane + 64];          // row g+1
    const float2 x = ((const float2*)(X + (size_t)s * HIDDEN))[lane];
    const float m0 = fmaf(t, b.x - a.x, a.x);
    const float m1v = fmaf(t, b.y - a.y, a.y);
    float* h = H + (size_t)d * HIDDEN + 2 * lane;
    atomicAdd(h + 0, m0 * x.x);
    atomicAdd(h + 1, m1v * x.y);
}

// ---------------------------------------------------------------------------
// Kernel 3: fused node MLP: out = relu(H@U1 + b1)@U2 + b2.
// 256 threads/block = 4 waves; each wave owns 8 rows, each lane 2 columns.
// U read from global (L2-cached, 64KB each); H rows staged in LDS, read as
// float4 broadcasts (register blocking: 1 U-float2 serves 8 rows).
// ---------------------------------------------------------------------------
#define NROWS 32
#define RPW 8

__global__ __launch_bounds__(256) void node_mlp(
    const float* __restrict__ H, const float* __restrict__ U1,
    const float* __restrict__ b1, const float* __restrict__ U2,
    const float* __restrict__ b2, float* __restrict__ out, int V) {
    __shared__ float hs[NROWS * HIDDEN];
    __shared__ float ts[NROWS * HIDDEN];
    const int tid = threadIdx.x;
    const int lane = tid & 63;
    const int wave = tid >> 6;
    const int r0 = blockIdx.x * NROWS;

    // stage 32 rows of H (zero-fill past V)
    const float4* Hg4 = (const float4*)(H + (size_t)r0 * HIDDEN);
    float4* hs4 = (float4*)hs;
    const long long max4 = (long long)(V - r0) * (HIDDEN / 4);
#pragma unroll
    for (int i = 0; i < 4; ++i) {
        const int idx = tid + i * 256;  // 0..1023
        float4 v = make_float4(0.f, 0.f, 0.f, 0.f);
        if (idx < max4) v = Hg4[idx];
        hs4[idx] = v;
    }
    __syncthreads();

    const float2* U1g = (const float2*)U1;
    const float2* U2g = (const float2*)U2;
    const float2 bb1 = ((const float2*)b1)[lane];
    const float2 bb2 = ((const float2*)b2)[lane];
    const int lr0 = wave * RPW;

    float2 acc[RPW];
#pragma unroll
    for (int j = 0; j < RPW; ++j) acc[j] = bb1;
    for (int k4 = 0; k4 < HIDDEN / 4; ++k4) {
        const float2 u0 = U1g[(k4 * 4 + 0) * 64 + lane];
        const float2 u1 = U1g[(k4 * 4 + 1) * 64 + lane];
        const float2 u2 = U1g[(k4 * 4 + 2) * 64 + lane];
        const float2 u3 = U1g[(k4 * 4 + 3) * 64 + lane];
#pragma unroll
        for (int j = 0; j < RPW; ++j) {
            const float4 h4 = *(const float4*)&hs[(lr0 + j) * HIDDEN + k4 * 4];
            acc[j].x = fmaf(h4.x, u0.x, acc[j].x);
            acc[j].y = fmaf(h4.x, u0.y, acc[j].y);
            acc[j].x = fmaf(h4.y, u1.x, acc[j].x);
            acc[j].y = fmaf(h4.y, u1.y, acc[j].y);
            acc[j].x = fmaf(h4.z, u2.x, acc[j].x);
            acc[j].y = fmaf(h4.z, u2.y, acc[j].y);
            acc[j].x = fmaf(h4.w, u3.x, acc[j].x);
            acc[j].y = fmaf(h4.w, u3.y, acc[j].y);
        }
    }
#pragma unroll
    for (int j = 0; j < RPW; ++j) {
        float2 t;
        t.x = fmaxf(acc[j].x, 0.0f);
        t.y = fmaxf(acc[j].y, 0.0f);
        *(float2*)&ts[(lr0 + j) * HIDDEN + 2 * lane] = t;
    }
    __syncthreads();

#pragma unroll
    for (int j = 0; j < RPW; ++j) acc[j] = bb2;
    for (int k4 = 0; k4 < HIDDEN / 4; ++k4) {
        const float2 u0 = U2g[(k4 * 4 + 0) * 64 + lane];
        const float2 u1 = U2g[(k4 * 4 + 1) * 64 + lane];
        const float2 u2 = U2g[(k4 * 4 + 2) * 64 + lane];
        const float2 u3 = U2g[(k4 * 4 + 3) * 64 + lane];
#pragma unroll
        for (int j = 0; j < RPW; ++j) {
            const float4 h4 = *(const float4*)&ts[(lr0 + j) * HIDDEN + k4 * 4];
            acc[j].x = fmaf(h4.x, u0.x, acc[j].x);
            acc[j].y = fmaf(h4.x, u0.y, acc[j].y);
            acc[j].x = fmaf(h4.y, u1.x, acc[j].x);
            acc[j].y = fmaf(h4.y, u1.y, acc[j].y);
            acc[j].x = fmaf(h4.z, u2.x, acc[j].x);
            acc[j].y = fmaf(h4.z, u2.y, acc[j].y);
            acc[j].x = fmaf(h4.w, u3.x, acc[j].x);
            acc[j].y = fmaf(h4.w, u3.y, acc[j].y);
        }
    }
    float2* out2 = (float2*)out;
#pragma unroll
    for (int j = 0; j < RPW; ++j) {
        const int row = r0 + lr0 + j;
        if (row < V) out2[(size_t)row * 64 + lane] = acc[j];
    }
}

// ---------------------------------------------------------------------------
extern "C" void kernel_launch(void* const* d_in, const int* in_sizes, int n_in,
                              void* d_out, int out_size, void* d_ws, size_t ws_size,
                              hipStream_t stream) {
    const float* X = (const float*)d_in[0];
    const float* R = (const float*)d_in[1];
    const int* src = (const int*)d_in[2];
    const int* dest = (const int*)d_in[3];
    const float* W1 = (const float*)d_in[4];
    const float* W2 = (const float*)d_in[5];
    const float* U1 = (const float*)d_in[6];
    const float* b1 = (const float*)d_in[7];
    const float* U2 = (const float*)d_in[8];
    const float* b2 = (const float*)d_in[9];

    const int V = in_sizes[0] / HIDDEN;
    const int E = in_sizes[2];

    float* Hbuf = (float*)d_ws;                        // [V,128]
    float* T = Hbuf + (size_t)V * HIDDEN;              // [TPTS,128]

    hipMemsetAsync(Hbuf, 0, (size_t)V * HIDDEN * sizeof(float), stream);
    build_table<<<TPTS, HIDDEN, 0, stream>>>(W1, W2, T);
    edge_scatter<<<(E + 3) / 4, 256, 0, stream>>>(R, src, dest, X, T, Hbuf, E);
    node_mlp<<<(V + NROWS - 1) / NROWS, 256, 0, stream>>>(Hbuf, U1, b1, U2, b2,
                                                          (float*)d_out, V);
}

// Round 2
// 312.371 us; speedup vs baseline: 2.4445x; 2.4445x over previous
//
#include <hip/hip_runtime.h>
#include <hip/hip_bf16.h>

#define HIDDEN 128
#define NB 64
#define TG 8192             // table cells
#define TPTS (TG + 1)       // table points
#define TMAX 32.0f
#define TINV ((float)TG / TMAX)   // 256 cells per unit of squared distance
#define VPAD 53248          // 13 * 4096, >= V+1, multiple of 4096 for the scan

// ---------------------------------------------------------------------------
// Kernel 1: tabulate the filter network M(d2) = relu(relu(rbf(d2)@W1)@W2)
// on a uniform grid over [0, TMAX]. One block per grid point, 128 threads.
// ---------------------------------------------------------------------------
__global__ void build_table(const float* __restrict__ W1,
                            const float* __restrict__ W2,
                            float* __restrict__ T) {
    __shared__ float rbf[NB];
    __shared__ float m1[HIDDEN];
    const int g = blockIdx.x;       // 0 .. TPTS-1
    const int c = threadIdx.x;      // 0 .. 127
    const float d = (float)g * (TMAX / (float)TG);
    if (c < NB) {
        const float center = 25.0f * (float)c / 63.0f;
        const float w = 25.0f / 63.0f;
        const float z = d - center;
        rbf[c] = expf(-(z * z) / (2.0f * w * w));
    }
    __syncthreads();
    float acc = 0.0f;
#pragma unroll
    for (int b = 0; b < NB; ++b) acc = fmaf(rbf[b], W1[b * HIDDEN + c], acc);
    m1[c] = fmaxf(acc, 0.0f);
    __syncthreads();
    float acc2 = 0.0f;
#pragma unroll 8
    for (int k = 0; k < HIDDEN; ++k) acc2 = fmaf(m1[k], W2[k * HIDDEN + c], acc2);
    T[(size_t)g * HIDDEN + c] = fmaxf(acc2, 0.0f);
}

// ---------------------------------------------------------------------------
// CSR build: histogram of dest
// ---------------------------------------------------------------------------
__global__ __launch_bounds__(256) void hist_dest(const int* __restrict__ dest,
                                                 int* __restrict__ cnt, int E) {
    const int e = blockIdx.x * blockDim.x + threadIdx.x;
    if (e < E) atomicAdd(&cnt[dest[e]], 1);
}

// ---------------------------------------------------------------------------
// Exclusive scan over VPAD counts (single block, 1024 threads, int4 + shfl).
// Writes exclusive offsets to both starts[] and cursor[].
// ---------------------------------------------------------------------------
__global__ __launch_bounds__(1024) void scan_counts(const int* __restrict__ cnt,
                                                    int* __restrict__ starts,
                                                    int* __restrict__ cursor) {
    __shared__ int wsum[16];
    __shared__ int chunk_carry;
    const int tid = threadIdx.x;
    const int lane = tid & 63;
    const int wv = tid >> 6;
    if (tid == 0) chunk_carry = 0;
    __syncthreads();
    for (int base = 0; base < VPAD; base += 4096) {
        const int i0 = base + tid * 4;
        const int4 c = *(const int4*)(cnt + i0);
        const int s1 = c.x + c.y;
        const int s2 = s1 + c.z;
        const int s3 = s2 + c.w;
        int s = s3;
#pragma unroll
        for (int d = 1; d < 64; d <<= 1) {
            const int n = __shfl_up(s, d);
            if (lane >= d) s += n;
        }
        if (lane == 63) wsum[wv] = s;
        __syncthreads();
        int woff = 0;
#pragma unroll
        for (int w = 0; w < 16; ++w)
            if (w < wv) woff += wsum[w];
        const int excl = chunk_carry + woff + (s - s3);
        int4 o;
        o.x = excl;
        o.y = excl + c.x;
        o.z = excl + s1;
        o.w = excl + s2;
        *(int4*)(starts + i0) = o;
        *(int4*)(cursor + i0) = o;
        __syncthreads();
        if (tid == 0) {
            int tot = 0;
#pragma unroll
            for (int w = 0; w < 16; ++w) tot += wsum[w];
            chunk_carry += tot;
        }
        __syncthreads();
    }
}

// ---------------------------------------------------------------------------
// Scatter edges into CSR order; precompute table coordinate u per edge.
// One int atomic per edge (returning), two 4B scattered payload writes.
// ---------------------------------------------------------------------------
__global__ __launch_bounds__(256) void scatter_edges(
    const int* __restrict__ src, const int* __restrict__ dest,
    const float* __restrict__ R, int* __restrict__ cursor,
    int* __restrict__ es, float* __restrict__ eu, int E) {
    const int e = blockIdx.x * blockDim.x + threadIdx.x;
    if (e >= E) return;
    const int s = src[e];
    const int d = dest[e];
    const float dx = R[3 * s + 0] - R[3 * d + 0];
    const float dy = R[3 * s + 1] - R[3 * d + 1];
    const float dz = R[3 * s + 2] - R[3 * d + 2];
    const float D2 = fmaf(dx, dx, fmaf(dy, dy, dz * dz));
    const float u = fminf(D2 * TINV, (float)TG);
    const int pos = atomicAdd(&cursor[d], 1);
    es[pos] = s;
    eu[pos] = u;
}

// ---------------------------------------------------------------------------
// Gather-accumulate: one wave per dest node. No FP atomics; H written once.
// ---------------------------------------------------------------------------
__global__ __launch_bounds__(256) void gather_accum(
    const int* __restrict__ starts, const int* __restrict__ es,
    const float* __restrict__ eu, const float* __restrict__ X,
    const float* __restrict__ T, float* __restrict__ H, int V) {
    const int node = blockIdx.x * 4 + (threadIdx.x >> 6);
    const int lane = threadIdx.x & 63;
    if (node >= V) return;
    const int beg = starts[node];
    const int end = starts[node + 1];
    float2 acc = make_float2(0.0f, 0.0f);
    for (int i = beg; i < end; ++i) {
        const int s = es[i];
        const float u = eu[i];
        int g = (int)u;
        if (g > TG - 1) g = TG - 1;
        const float t = u - (float)g;
        const float2* trow = (const float2*)(T + (size_t)g * HIDDEN);
        const float2 a = trow[lane];
        const float2 b = trow[lane + 64];     // row g+1
        const float2 x = ((const float2*)(X + (size_t)s * HIDDEN))[lane];
        const float m0 = fmaf(t, b.x - a.x, a.x);
        const float m1 = fmaf(t, b.y - a.y, a.y);
        acc.x = fmaf(m0, x.x, acc.x);
        acc.y = fmaf(m1, x.y, acc.y);
    }
    ((float2*)(H + (size_t)node * HIDDEN))[lane] = acc;
}

// ---------------------------------------------------------------------------
// Fused node MLP: out = relu(H@U1 + b1)@U2 + b2.  (unchanged from R0)
// ---------------------------------------------------------------------------
#define NROWS 32
#define RPW 8

__global__ __launch_bounds__(256) void node_mlp(
    const float* __restrict__ H, const float* __restrict__ U1,
    const float* __restrict__ b1, const float* __restrict__ U2,
    const float* __restrict__ b2, float* __restrict__ out, int V) {
    __shared__ float hs[NROWS * HIDDEN];
    __shared__ float ts[NROWS * HIDDEN];
    const int tid = threadIdx.x;
    const int lane = tid & 63;
    const int wave = tid >> 6;
    const int r0 = blockIdx.x * NROWS;

    const float4* Hg4 = (const float4*)(H + (size_t)r0 * HIDDEN);
    float4* hs4 = (float4*)hs;
    const long long max4 = (long long)(V - r0) * (HIDDEN / 4);
#pragma unroll
    for (int i = 0; i < 4; ++i) {
        const int idx = tid + i * 256;
        float4 v = make_float4(0.f, 0.f, 0.f, 0.f);
        if (idx < max4) v = Hg4[idx];
        hs4[idx] = v;
    }
    __syncthreads();

    const float2* U1g = (const float2*)U1;
    const float2* U2g = (const float2*)U2;
    const float2 bb1 = ((const float2*)b1)[lane];
    const float2 bb2 = ((const float2*)b2)[lane];
    const int lr0 = wave * RPW;

    float2 acc[RPW];
#pragma unroll
    for (int j = 0; j < RPW; ++j) acc[j] = bb1;
    for (int k4 = 0; k4 < HIDDEN / 4; ++k4) {
        const float2 u0 = U1g[(k4 * 4 + 0) * 64 + lane];
        const float2 u1 = U1g[(k4 * 4 + 1) * 64 + lane];
        const float2 u2 = U1g[(k4 * 4 + 2) * 64 + lane];
        const float2 u3 = U1g[(k4 * 4 + 3) * 64 + lane];
#pragma unroll
        for (int j = 0; j < RPW; ++j) {
            const float4 h4 = *(const float4*)&hs[(lr0 + j) * HIDDEN + k4 * 4];
            acc[j].x = fmaf(h4.x, u0.x, acc[j].x);
            acc[j].y = fmaf(h4.x, u0.y, acc[j].y);
            acc[j].x = fmaf(h4.y, u1.x, acc[j].x);
            acc[j].y = fmaf(h4.y, u1.y, acc[j].y);
            acc[j].x = fmaf(h4.z, u2.x, acc[j].x);
            acc[j].y = fmaf(h4.z, u2.y, acc[j].y);
            acc[j].x = fmaf(h4.w, u3.x, acc[j].x);
            acc[j].y = fmaf(h4.w, u3.y, acc[j].y);
        }
    }
#pragma unroll
    for (int j = 0; j < RPW; ++j) {
        float2 t;
        t.x = fmaxf(acc[j].x, 0.0f);
        t.y = fmaxf(acc[j].y, 0.0f);
        *(float2*)&ts[(lr0 + j) * HIDDEN + 2 * lane] = t;
    }
    __syncthreads();

#pragma unroll
    for (int j = 0; j < RPW; ++j) acc[j] = bb2;
    for (int k4 = 0; k4 < HIDDEN / 4; ++k4) {
        const float2 u0 = U2g[(k4 * 4 + 0) * 64 + lane];
        const float2 u1 = U2g[(k4 * 4 + 1) * 64 + lane];
        const float2 u2 = U2g[(k4 * 4 + 2) * 64 + lane];
        const float2 u3 = U2g[(k4 * 4 + 3) * 64 + lane];
#pragma unroll
        for (int j = 0; j < RPW; ++j) {
            const float4 h4 = *(const float4*)&ts[(lr0 + j) * HIDDEN + k4 * 4];
            acc[j].x = fmaf(h4.x, u0.x, acc[j].x);
            acc[j].y = fmaf(h4.x, u0.y, acc[j].y);
            acc[j].x = fmaf(h4.y, u1.x, acc[j].x);
            acc[j].y = fmaf(h4.y, u1.y, acc[j].y);
            acc[j].x = fmaf(h4.z, u2.x, acc[j].x);
            acc[j].y = fmaf(h4.z, u2.y, acc[j].y);
            acc[j].x = fmaf(h4.w, u3.x, acc[j].x);
            acc[j].y = fmaf(h4.w, u3.y, acc[j].y);
        }
    }
    float2* out2 = (float2*)out;
#pragma unroll
    for (int j = 0; j < RPW; ++j) {
        const int row = r0 + lr0 + j;
        if (row < V) out2[(size_t)row * 64 + lane] = acc[j];
    }
}

// ---------------------------------------------------------------------------
extern "C" void kernel_launch(void* const* d_in, const int* in_sizes, int n_in,
                              void* d_out, int out_size, void* d_ws, size_t ws_size,
                              hipStream_t stream) {
    const float* X = (const float*)d_in[0];
    const float* R = (const float*)d_in[1];
    const int* src = (const int*)d_in[2];
    const int* dest = (const int*)d_in[3];
    const float* W1 = (const float*)d_in[4];
    const float* W2 = (const float*)d_in[5];
    const float* U1 = (const float*)d_in[6];
    const float* b1 = (const float*)d_in[7];
    const float* U2 = (const float*)d_in[8];
    const float* b2 = (const float*)d_in[9];

    const int V = in_sizes[0] / HIDDEN;
    const int E = in_sizes[2];

    // workspace layout (16B-aligned sections)
    char* base = (char*)d_ws;
    float* Hbuf = (float*)base;                 base += (size_t)V * HIDDEN * sizeof(float);
    float* T = (float*)base;                    base += (size_t)TPTS * HIDDEN * sizeof(float);
    int* cnt = (int*)base;                      base += (size_t)VPAD * sizeof(int);
    int* starts = (int*)base;                   base += (size_t)VPAD * sizeof(int);
    int* cursor = (int*)base;                   base += (size_t)VPAD * sizeof(int);
    int* es = (int*)base;                       base += (size_t)E * sizeof(int);
    float* eu = (float*)base;

    hipMemsetAsync(cnt, 0, (size_t)VPAD * sizeof(int), stream);
    build_table<<<TPTS, HIDDEN, 0, stream>>>(W1, W2, T);
    hist_dest<<<(E + 255) / 256, 256, 0, stream>>>(dest, cnt, E);
    scan_counts<<<1, 1024, 0, stream>>>(cnt, starts, cursor);
    scatter_edges<<<(E + 255) / 256, 256, 0, stream>>>(src, dest, R, cursor, es, eu, E);
    gather_accum<<<(V + 3) / 4, 256, 0, stream>>>(starts, es, eu, X, T, Hbuf, V);
    node_mlp<<<(V + NROWS - 1) / NROWS, 256, 0, stream>>>(Hbuf, U1, b1, U2, b2,
                                                          (float*)d_out, V);
}

// Round 3
// 297.322 us; speedup vs baseline: 2.5682x; 1.0506x over previous
//
#include <hip/hip_runtime.h>
#include <hip/hip_bf16.h>

#define HIDDEN 128
#define NB 64
#define TG 4096             // table cells
#define TPTS (TG + 1)       // table points
#define TMAX 32.0f
#define TINV ((float)TG / TMAX)   // 128 cells per unit of squared distance
#define VPAD 53248          // 13 * 4096, >= V+1, multiple of 4096 for the scan

// ---------------------------------------------------------------------------
// Kernel 0: transpose W1 [64,128] -> W1T [128,64], W2 [128,128] -> W2T [128,128]
// so build_table can read weight columns contiguously.
// ---------------------------------------------------------------------------
__global__ __launch_bounds__(256) void transpose_w(const float* __restrict__ W1,
                                                   const float* __restrict__ W2,
                                                   float* __restrict__ W1T,
                                                   float* __restrict__ W2T) {
    const int i = blockIdx.x * 256 + threadIdx.x;
    if (i < NB * HIDDEN) {
        const int b = i >> 7, c = i & 127;
        W1T[c * NB + b] = W1[i];
    }
    if (i < HIDDEN * HIDDEN) {
        const int k = i >> 7, c = i & 127;
        W2T[c * HIDDEN + k] = W2[i];
    }
}

// ---------------------------------------------------------------------------
// Kernel 1: tabulate M(d2) = relu(relu(rbf(d2)@W1)@W2) on a uniform grid over
// [0, TMAX], writing the interleaved-pair table Tp[g][c] = {T[g][c], T[g+1][c]}.
// One block per grid point, 128 threads; weights read as contiguous float4.
// ---------------------------------------------------------------------------
__global__ __launch_bounds__(128) void build_table(const float* __restrict__ W1T,
                                                   const float* __restrict__ W2T,
                                                   float2* __restrict__ Tp) {
    __shared__ float rbf[NB];
    __shared__ float m1[HIDDEN];
    const int g = blockIdx.x;       // 0 .. TPTS-1
    const int c = threadIdx.x;      // 0 .. 127
    const float d = (float)g * (TMAX / (float)TG);
    if (c < NB) {
        const float center = 25.0f * (float)c / 63.0f;
        const float w = 25.0f / 63.0f;
        const float z = d - center;
        rbf[c] = expf(-(z * z) / (2.0f * w * w));
    }
    __syncthreads();
    const float4* w1 = (const float4*)(W1T + c * NB);
    float acc = 0.0f;
#pragma unroll
    for (int b4 = 0; b4 < NB / 4; ++b4) {
        const float4 w = w1[b4];
        acc = fmaf(rbf[4 * b4 + 0], w.x, acc);
        acc = fmaf(rbf[4 * b4 + 1], w.y, acc);
        acc = fmaf(rbf[4 * b4 + 2], w.z, acc);
        acc = fmaf(rbf[4 * b4 + 3], w.w, acc);
    }
    m1[c] = fmaxf(acc, 0.0f);
    __syncthreads();
    const float4* w2 = (const float4*)(W2T + c * HIDDEN);
    float acc2 = 0.0f;
#pragma unroll 8
    for (int k4 = 0; k4 < HIDDEN / 4; ++k4) {
        const float4 w = w2[k4];
        acc2 = fmaf(m1[4 * k4 + 0], w.x, acc2);
        acc2 = fmaf(m1[4 * k4 + 1], w.y, acc2);
        acc2 = fmaf(m1[4 * k4 + 2], w.z, acc2);
        acc2 = fmaf(m1[4 * k4 + 3], w.w, acc2);
    }
    const float v = fmaxf(acc2, 0.0f);
    if (g < TG) Tp[(size_t)g * HIDDEN + c].x = v;        // point g of cell g
    if (g >= 1) Tp[(size_t)(g - 1) * HIDDEN + c].y = v;  // point g of cell g-1
}

// ---------------------------------------------------------------------------
// CSR build: histogram of dest
// ---------------------------------------------------------------------------
__global__ __launch_bounds__(256) void hist_dest(const int* __restrict__ dest,
                                                 int* __restrict__ cnt, int E) {
    const int e = blockIdx.x * blockDim.x + threadIdx.x;
    if (e < E) atomicAdd(&cnt[dest[e]], 1);
}

// ---------------------------------------------------------------------------
// Exclusive scan over VPAD counts (single block, 1024 threads, int4 + shfl).
// ---------------------------------------------------------------------------
__global__ __launch_bounds__(1024) void scan_counts(const int* __restrict__ cnt,
                                                    int* __restrict__ starts,
                                                    int* __restrict__ cursor) {
    __shared__ int wsum[16];
    __shared__ int chunk_carry;
    const int tid = threadIdx.x;
    const int lane = tid & 63;
    const int wv = tid >> 6;
    if (tid == 0) chunk_carry = 0;
    __syncthreads();
    for (int base = 0; base < VPAD; base += 4096) {
        const int i0 = base + tid * 4;
        const int4 c = *(const int4*)(cnt + i0);
        const int s1 = c.x + c.y;
        const int s2 = s1 + c.z;
        const int s3 = s2 + c.w;
        int s = s3;
#pragma unroll
        for (int d = 1; d < 64; d <<= 1) {
            const int n = __shfl_up(s, d);
            if (lane >= d) s += n;
        }
        if (lane == 63) wsum[wv] = s;
        __syncthreads();
        int woff = 0;
#pragma unroll
        for (int w = 0; w < 16; ++w)
            if (w < wv) woff += wsum[w];
        const int excl = chunk_carry + woff + (s - s3);
        int4 o;
        o.x = excl;
        o.y = excl + c.x;
        o.z = excl + s1;
        o.w = excl + s2;
        *(int4*)(starts + i0) = o;
        *(int4*)(cursor + i0) = o;
        __syncthreads();
        if (tid == 0) {
            int tot = 0;
#pragma unroll
            for (int w = 0; w < 16; ++w) tot += wsum[w];
            chunk_carry += tot;
        }
        __syncthreads();
    }
}

// ---------------------------------------------------------------------------
// Scatter edges into CSR order; pack {src, u} into ONE float2 (one cacheline).
// ---------------------------------------------------------------------------
__global__ __launch_bounds__(256) void scatter_edges(
    const int* __restrict__ src, const int* __restrict__ dest,
    const float* __restrict__ R, int* __restrict__ cursor,
    float2* __restrict__ ep, int E) {
    const int e = blockIdx.x * blockDim.x + threadIdx.x;
    if (e >= E) return;
    const int s = src[e];
    const int d = dest[e];
    const float dx = R[3 * s + 0] - R[3 * d + 0];
    const float dy = R[3 * s + 1] - R[3 * d + 1];
    const float dz = R[3 * s + 2] - R[3 * d + 2];
    const float D2 = fmaf(dx, dx, fmaf(dy, dy, dz * dz));
    const float u = fminf(D2 * TINV, (float)TG);
    const int pos = atomicAdd(&cursor[d], 1);
    ep[pos] = make_float2(__int_as_float(s), u);
}

// ---------------------------------------------------------------------------
// Gather-accumulate: one wave per dest node, 2-edge unroll, single float4
// table load per edge (interleaved-pair layout). No FP atomics.
// ---------------------------------------------------------------------------
__global__ __launch_bounds__(256) void gather_accum(
    const int* __restrict__ starts, const float2* __restrict__ ep,
    const float* __restrict__ X, const float4* __restrict__ Tp4,
    float* __restrict__ H, int V) {
    const int node = blockIdx.x * 4 + (threadIdx.x >> 6);
    const int lane = threadIdx.x & 63;
    if (node >= V) return;
    const int beg = starts[node];
    const int end = starts[node + 1];
    const float2* X2 = (const float2*)X;
    float2 acc = make_float2(0.0f, 0.0f);
    int i = beg;
    for (; i + 2 <= end; i += 2) {
        const float2 e0 = ep[i];
        const float2 e1 = ep[i + 1];
        const int s0 = __float_as_int(e0.x);
        const int s1 = __float_as_int(e1.x);
        int g0 = (int)e0.y; if (g0 > TG - 1) g0 = TG - 1;
        int g1 = (int)e1.y; if (g1 > TG - 1) g1 = TG - 1;
        const float t0 = e0.y - (float)g0;
        const float t1 = e1.y - (float)g1;
        const float4 q0 = Tp4[(size_t)g0 * 64 + lane];
        const float4 q1 = Tp4[(size_t)g1 * 64 + lane];
        const float2 x0 = X2[(size_t)s0 * 64 + lane];
        const float2 x1 = X2[(size_t)s1 * 64 + lane];
        acc.x = fmaf(fmaf(t0, q0.y - q0.x, q0.x), x0.x, acc.x);
        acc.y = fmaf(fmaf(t0, q0.w - q0.z, q0.z), x0.y, acc.y);
        acc.x = fmaf(fmaf(t1, q1.y - q1.x, q1.x), x1.x, acc.x);
        acc.y = fmaf(fmaf(t1, q1.w - q1.z, q1.z), x1.y, acc.y);
    }
    if (i < end) {
        const float2 e0 = ep[i];
        const int s0 = __float_as_int(e0.x);
        int g0 = (int)e0.y; if (g0 > TG - 1) g0 = TG - 1;
        const float t0 = e0.y - (float)g0;
        const float4 q0 = Tp4[(size_t)g0 * 64 + lane];
        const float2 x0 = X2[(size_t)s0 * 64 + lane];
        acc.x = fmaf(fmaf(t0, q0.y - q0.x, q0.x), x0.x, acc.x);
        acc.y = fmaf(fmaf(t0, q0.w - q0.z, q0.z), x0.y, acc.y);
    }
    ((float2*)H)[(size_t)node * 64 + lane] = acc;
}

// ---------------------------------------------------------------------------
// Fused node MLP: out = relu(H@U1 + b1)@U2 + b2.
// ---------------------------------------------------------------------------
#define NROWS 32
#define RPW 8

__global__ __launch_bounds__(256) void node_mlp(
    const float* __restrict__ H, const float* __restrict__ U1,
    const float* __restrict__ b1, const float* __restrict__ U2,
    const float* __restrict__ b2, float* __restrict__ out, int V) {
    __shared__ float hs[NROWS * HIDDEN];
    __shared__ float ts[NROWS * HIDDEN];
    const int tid = threadIdx.x;
    const int lane = tid & 63;
    const int wave = tid >> 6;
    const int r0 = blockIdx.x * NROWS;

    const float4* Hg4 = (const float4*)(H + (size_t)r0 * HIDDEN);
    float4* hs4 = (float4*)hs;
    const long long max4 = (long long)(V - r0) * (HIDDEN / 4);
#pragma unroll
    for (int i = 0; i < 4; ++i) {
        const int idx = tid + i * 256;
        float4 v = make_float4(0.f, 0.f, 0.f, 0.f);
        if (idx < max4) v = Hg4[idx];
        hs4[idx] = v;
    }
    __syncthreads();

    const float2* U1g = (const float2*)U1;
    const float2* U2g = (const float2*)U2;
    const float2 bb1 = ((const float2*)b1)[lane];
    const float2 bb2 = ((const float2*)b2)[lane];
    const int lr0 = wave * RPW;

    float2 acc[RPW];
#pragma unroll
    for (int j = 0; j < RPW; ++j) acc[j] = bb1;
    for (int k4 = 0; k4 < HIDDEN / 4; ++k4) {
        const float2 u0 = U1g[(k4 * 4 + 0) * 64 + lane];
        const float2 u1 = U1g[(k4 * 4 + 1) * 64 + lane];
        const float2 u2 = U1g[(k4 * 4 + 2) * 64 + lane];
        const float2 u3 = U1g[(k4 * 4 + 3) * 64 + lane];
#pragma unroll
        for (int j = 0; j < RPW; ++j) {
            const float4 h4 = *(const float4*)&hs[(lr0 + j) * HIDDEN + k4 * 4];
            acc[j].x = fmaf(h4.x, u0.x, acc[j].x);
            acc[j].y = fmaf(h4.x, u0.y, acc[j].y);
            acc[j].x = fmaf(h4.y, u1.x, acc[j].x);
            acc[j].y = fmaf(h4.y, u1.y, acc[j].y);
            acc[j].x = fmaf(h4.z, u2.x, acc[j].x);
            acc[j].y = fmaf(h4.z, u2.y, acc[j].y);
            acc[j].x = fmaf(h4.w, u3.x, acc[j].x);
            acc[j].y = fmaf(h4.w, u3.y, acc[j].y);
        }
    }
#pragma unroll
    for (int j = 0; j < RPW; ++j) {
        float2 t;
        t.x = fmaxf(acc[j].x, 0.0f);
        t.y = fmaxf(acc[j].y, 0.0f);
        *(float2*)&ts[(lr0 + j) * HIDDEN + 2 * lane] = t;
    }
    __syncthreads();

#pragma unroll
    for (int j = 0; j < RPW; ++j) acc[j] = bb2;
    for (int k4 = 0; k4 < HIDDEN / 4; ++k4) {
        const float2 u0 = U2g[(k4 * 4 + 0) * 64 + lane];
        const float2 u1 = U2g[(k4 * 4 + 1) * 64 + lane];
        const float2 u2 = U2g[(k4 * 4 + 2) * 64 + lane];
        const float2 u3 = U2g[(k4 * 4 + 3) * 64 + lane];
#pragma unroll
        for (int j = 0; j < RPW; ++j) {
            const float4 h4 = *(const float4*)&ts[(lr0 + j) * HIDDEN + k4 * 4];
            acc[j].x = fmaf(h4.x, u0.x, acc[j].x);
            acc[j].y = fmaf(h4.x, u0.y, acc[j].y);
            acc[j].x = fmaf(h4.y, u1.x, acc[j].x);
            acc[j].y = fmaf(h4.y, u1.y, acc[j].y);
            acc[j].x = fmaf(h4.z, u2.x, acc[j].x);
            acc[j].y = fmaf(h4.z, u2.y, acc[j].y);
            acc[j].x = fmaf(h4.w, u3.x, acc[j].x);
            acc[j].y = fmaf(h4.w, u3.y, acc[j].y);
        }
    }
    float2* out2 = (float2*)out;
#pragma unroll
    for (int j = 0; j < RPW; ++j) {
        const int row = r0 + lr0 + j;
        if (row < V) out2[(size_t)row * 64 + lane] = acc[j];
    }
}

// ---------------------------------------------------------------------------
extern "C" void kernel_launch(void* const* d_in, const int* in_sizes, int n_in,
                              void* d_out, int out_size, void* d_ws, size_t ws_size,
                              hipStream_t stream) {
    const float* X = (const float*)d_in[0];
    const float* R = (const float*)d_in[1];
    const int* src = (const int*)d_in[2];
    const int* dest = (const int*)d_in[3];
    const float* W1 = (const float*)d_in[4];
    const float* W2 = (const float*)d_in[5];
    const float* U1 = (const float*)d_in[6];
    const float* b1 = (const float*)d_in[7];
    const float* U2 = (const float*)d_in[8];
    const float* b2 = (const float*)d_in[9];

    const int V = in_sizes[0] / HIDDEN;
    const int E = in_sizes[2];

    // workspace layout (16B-aligned sections)
    char* base = (char*)d_ws;
    float* Hbuf = (float*)base;                 base += (size_t)V * HIDDEN * sizeof(float);
    float2* Tp = (float2*)base;                 base += (size_t)TG * HIDDEN * sizeof(float2);
    float2* ep = (float2*)base;                 base += (size_t)E * sizeof(float2);
    int* cnt = (int*)base;                      base += (size_t)VPAD * sizeof(int);
    int* starts = (int*)base;                   base += (size_t)VPAD * sizeof(int);
    int* cursor = (int*)base;                   base += (size_t)VPAD * sizeof(int);
    float* W1T = (float*)base;                  base += (size_t)NB * HIDDEN * sizeof(float);
    float* W2T = (float*)base;

    hipMemsetAsync(cnt, 0, (size_t)VPAD * sizeof(int), stream);
    transpose_w<<<64, 256, 0, stream>>>(W1, W2, W1T, W2T);
    build_table<<<TPTS, HIDDEN, 0, stream>>>(W1T, W2T, Tp);
    hist_dest<<<(E + 255) / 256, 256, 0, stream>>>(dest, cnt, E);
    scan_counts<<<1, 1024, 0, stream>>>(cnt, starts, cursor);
    scatter_edges<<<(E + 255) / 256, 256, 0, stream>>>(src, dest, R, cursor, ep, E);
    gather_accum<<<(V + 3) / 4, 256, 0, stream>>>(starts, ep, X, (const float4*)Tp,
                                                  Hbuf, V);
    node_mlp<<<(V + NROWS - 1) / NROWS, 256, 0, stream>>>(Hbuf, U1, b1, U2, b2,
                                                          (float*)d_out, V);
}